// Round 1
// baseline (1135.421 us; speedup 1.0000x reference)
//
#include <hip/hip_runtime.h>
#include <math.h>

// ============================================================================
// ConcatenatedIrrepsTensorProduct — fused fp32, round 3.
//
// Round-2 counters: fused_tp 281.7us, VALUBusy 59%, Mfma 0, HBM 11%, conflicts
// 0, occupancy 38%. FMA floor is ~94us -> ~41% of time is barrier/latency
// stall, ~26% non-FMA VALU. This round restructures to a fully-pipelined
// 12-barrier schedule:
//   - sA double-buffer + FOUR B slots: every phase overlaps (stage next B /
//     build next A-tile) with the current gemm. No stage->use bubbles.
//   - x1 tail kept in 48 regs, loaded as 12 aligned float4 per thread
//     (window 32+3*u4 is 16B aligned). t1 + all three k-slices written from
//     regs; the 3 global re-read passes of round 2 are gone.
//   - o1 split: o1[e,w,k] = y1k*q2[e,w] + q3k[e,w], q2 = (pw*p2.g2)@C1top
//     computed once, q3k = (pw*y0*t3k.g3)@C1bot (k=32 gemms). -5% FMAs.
//   - 32-wide gated tiles in recycled B slots with XOR unit swizzle
//     (unit ^= e&7; per-thread constant -> folds into base address).
// LDS: 2*17408 (A) + 4*8192 (B) + 8192 (s32) + 1024 (sY) = 76800 B
//      -> 2 blocks/CU, 8 waves/CU.
// ============================================================================

#define TPB 256
#define ET  64
#define SAS 68   // sA row stride in floats: rows 16B-aligned, b128 conflict-free

#define FMA4(acc, s, b)                                         \
  acc.x = fmaf((s), (b).x, acc.x); acc.y = fmaf((s), (b).y, acc.y); \
  acc.z = fmaf((s), (b).z, acc.z); acc.w = fmaf((s), (b).w, acc.w)

// ---------------------------------------------------------------------------
// prep: SILU_CST integral (fp64 trapz identical to reference's np.trapz)
// ---------------------------------------------------------------------------
__global__ void zero_cst_kernel(double* cst) {
  if (threadIdx.x == 0) cst[0] = 0.0;
}

__global__ void cst_accum_kernel(double* cst) {
  __shared__ double red[256];
  double sum = 0.0;
  for (long i = (long)blockIdx.x * 256 + threadIdx.x; i <= 200000; i += 64L * 256) {
    double z = -12.0 + (double)i * (24.0 / 200000.0);
    double s = z / (1.0 + exp(-z));
    double phi = exp(-0.5 * z * z) * 0.3989422804014327;
    double f = s * s * phi;
    if (i == 0 || i == 200000) f *= 0.5;
    sum += f;
  }
  red[threadIdx.x] = sum;
  __syncthreads();
  for (int off = 128; off > 0; off >>= 1) {
    if (threadIdx.x < (unsigned)off) red[threadIdx.x] += red[threadIdx.x + off];
    __syncthreads();
  }
  if (threadIdx.x == 0) atomicAdd(cst, red[0]);
}

// ---------------------------------------------------------------------------
// prep: C0 = Wl0@Wf0 /(8*sqrt32), C1 = Wl1@Wf1 /(8*sqrt32)   (64x32 each)
// ---------------------------------------------------------------------------
__global__ void prep_C_kernel(const float* __restrict__ Wl0, const float* __restrict__ Wf0,
                              const float* __restrict__ Wl1, const float* __restrict__ Wf1,
                              float* __restrict__ C0, float* __restrict__ C1) {
  const float* Wl = blockIdx.x ? Wl1 : Wl0;
  const float* Wf = blockIdx.x ? Wf1 : Wf0;
  float* C = blockIdx.x ? C1 : C0;
  for (int i = threadIdx.x; i < 64 * 32; i += 256) {
    int u = i >> 5, w = i & 31;
    float acc = 0.f;
#pragma unroll
    for (int v = 0; v < 32; ++v) acc = fmaf(Wl[u * 32 + v], Wf[v * 32 + w], acc);
    C[i] = acc * 0.022097086912079612f;  // 1/(sqrt(64)*sqrt(32))
  }
}

// ---------------------------------------------------------------------------
// device helpers
// ---------------------------------------------------------------------------
__device__ __forceinline__ void stageB(const float* __restrict__ g, int ncols, int col0,
                                       float* __restrict__ sB, int t) {
  // copy 64 x 32 column block of row-major [64][ncols] into sB[c*32+j]
#pragma unroll
  for (int r = 0; r < 2; ++r) {
    int i = (r * TPB + t) * 4;     // 0..2044 step 4
    int c = i >> 5, j = i & 31;
    *(float4*)(sB + i) = *(const float4*)(g + c * ncols + col0 + j);
  }
}

__device__ __forceinline__ void stageB32(const float* __restrict__ g, int row0,
                                         float* __restrict__ sB, int t) {
  // copy 32 x 32 row block of row-major [64][32] into sB[c*32+j]
  int i = t * 4;                   // 0..1020 step 4
  int c = i >> 5, j = i & 31;
  *(float4*)(sB + i) = *(const float4*)(g + (row0 + c) * 32 + j);
}

// out[e][4cg..4cg+3] for e in {e0l, e1l}: A stride SAS, B stride 32, k=64
__device__ __forceinline__ void gemm2(const float* __restrict__ sA,
                                      const float* __restrict__ sB,
                                      int e0l, int e1l, int cg,
                                      float4& out0, float4& out1) {
  float4 acc0 = make_float4(0.f, 0.f, 0.f, 0.f);
  float4 acc1 = make_float4(0.f, 0.f, 0.f, 0.f);
  const float* a0p = sA + e0l * SAS;
  const float* a1p = sA + e1l * SAS;
  const float* bp  = sB + 4 * cg;
#pragma unroll 4
  for (int c4 = 0; c4 < 16; ++c4) {
    float4 a0 = *(const float4*)(a0p + 4 * c4);
    float4 a1 = *(const float4*)(a1p + 4 * c4);
    const float* bb = bp + c4 * 128;
    float4 b0 = *(const float4*)(bb);
    float4 b1 = *(const float4*)(bb + 32);
    float4 b2 = *(const float4*)(bb + 64);
    float4 b3 = *(const float4*)(bb + 96);
    FMA4(acc0, a0.x, b0); FMA4(acc1, a1.x, b0);
    FMA4(acc0, a0.y, b1); FMA4(acc1, a1.y, b1);
    FMA4(acc0, a0.z, b2); FMA4(acc1, a1.z, b2);
    FMA4(acc0, a0.w, b3); FMA4(acc1, a1.w, b3);
  }
  out0 = acc0;
  out1 = acc1;
}

// k=32 gemm: A is a 64x32 tile, stride 32 floats, 16B units XOR-swizzled by
// (e&7) (per-thread constant) so stride-32 rows stay b128 conflict-free.
__device__ __forceinline__ void gemm32(const float* __restrict__ sAx,
                                       const float* __restrict__ sB,
                                       int e0l, int e1l, int cg,
                                       float4& out0, float4& out1) {
  float4 acc0 = make_float4(0.f, 0.f, 0.f, 0.f);
  float4 acc1 = make_float4(0.f, 0.f, 0.f, 0.f);
  const float* a0p = sAx + e0l * 32;
  const float* a1p = sAx + e1l * 32;
  const int x0 = (e0l & 7) << 2;
  const int x1 = (e1l & 7) << 2;
  const float* bp  = sB + 4 * cg;
#pragma unroll
  for (int c4 = 0; c4 < 8; ++c4) {
    float4 a0 = *(const float4*)(a0p + ((c4 << 2) ^ x0));
    float4 a1 = *(const float4*)(a1p + ((c4 << 2) ^ x1));
    const float* bb = bp + c4 * 128;
    float4 b0 = *(const float4*)(bb);
    float4 b1 = *(const float4*)(bb + 32);
    float4 b2 = *(const float4*)(bb + 64);
    float4 b3 = *(const float4*)(bb + 96);
    FMA4(acc0, a0.x, b0); FMA4(acc1, a1.x, b0);
    FMA4(acc0, a0.y, b1); FMA4(acc1, a1.y, b1);
    FMA4(acc0, a0.z, b2); FMA4(acc1, a1.z, b2);
    FMA4(acc0, a0.w, b3); FMA4(acc1, a1.w, b3);
  }
  out0 = acc0;
  out1 = acc1;
}

__device__ __forceinline__ void put32(float* __restrict__ sb, int e, int cg, float4 v) {
  *(float4*)(sb + e * 32 + ((cg ^ (e & 7)) << 2)) = v;
}

__device__ __forceinline__ float silu1(float x, float cst) {
  x *= 0.125f;
  return cst * x / (1.f + __expf(-x));
}

__device__ __forceinline__ float4 siluq(float4 v, float cst) {
  return make_float4(silu1(v.x, cst), silu1(v.y, cst), silu1(v.z, cst), silu1(v.w, cst));
}

__device__ __forceinline__ float4 muls(float4 a, float s) {
  return make_float4(a.x * s, a.y * s, a.z * s, a.w * s);
}

__device__ __forceinline__ float4 cmul(float4 a, float4 b, float s) {
  return make_float4(s * a.x * b.x, s * a.y * b.y, s * a.z * b.z, s * a.w * b.w);
}

// write k-slice kk of s1 from the register-cached x1 tail
#define S1K(dst, kk) do {                                                     \
  _Pragma("unroll")                                                           \
  for (int r = 0; r < 4; ++r) {                                               \
    int i = r * TPB + t; int e = i >> 4; int m = i & 15;                      \
    *(float4*)((dst) + e * SAS + 4 * m) =                                     \
      make_float4(xw[r][kk], xw[r][3 + kk], xw[r][6 + kk], xw[r][9 + kk]);    \
  }                                                                           \
} while (0)

// o1(k=kk) = y1k * q2 + q3k
#define COMBINE(kk, r0, r1) do {                                              \
  float ya = (kk == 0) ? yv0.y : (kk == 1) ? yv0.z : yv0.w;                   \
  float yb = (kk == 0) ? yv1.y : (kk == 1) ? yv1.z : yv1.w;                   \
  o1v[0][kk]     = ya * q2q[0].x + (r0).x;                                    \
  o1v[0][3 + kk] = ya * q2q[0].y + (r0).y;                                    \
  o1v[0][6 + kk] = ya * q2q[0].z + (r0).z;                                    \
  o1v[0][9 + kk] = ya * q2q[0].w + (r0).w;                                    \
  o1v[1][kk]     = yb * q2q[1].x + (r1).x;                                    \
  o1v[1][3 + kk] = yb * q2q[1].y + (r1).y;                                    \
  o1v[1][6 + kk] = yb * q2q[1].z + (r1).z;                                    \
  o1v[1][9 + kk] = yb * q2q[1].w + (r1).w;                                    \
} while (0)

// ---------------------------------------------------------------------------
// fused main kernel — 12-barrier pipelined schedule
// ---------------------------------------------------------------------------
__global__ __launch_bounds__(TPB, 2) void fused_tp(
    const float* __restrict__ x1a, const float* __restrict__ x1b,
    const float* __restrict__ x2, const float* __restrict__ scalars,
    const float* __restrict__ w0, const float* __restrict__ w1,
    const float* __restrict__ w2, const float* __restrict__ w3,
    const float* __restrict__ Wm1, const float* __restrict__ Wm2,
    const float* __restrict__ Wm3, const float* __restrict__ C0,
    const float* __restrict__ C1, const double* __restrict__ cstp,
    float* __restrict__ out) {
  __shared__ __align__(16) float sA0[ET * SAS];   // 17408 B
  __shared__ __align__(16) float sA1[ET * SAS];   // 17408 B
  __shared__ __align__(16) float sBB[4][64 * 32]; // 32768 B
  __shared__ __align__(16) float s32[64 * 32];    //  8192 B (swizzled 32-wide)
  __shared__ __align__(16) float sY[ET * 4];      //  1024 B

  const int t  = threadIdx.x;
  const int cg = t & 7;            // 0..7  column group (4 cols)
  const int eh = t >> 3;           // 0..31 first event; second is eh+32
  const long e0 = (long)blockIdx.x * ET;
  const float cst = (float)(1.0 / sqrt(cstp[0] * (24.0 / 200000.0)));

  const float pw   = 0.125f;
  const float pws3 = 0.125f * 0.57735026918962576f;

  // ---- P0: stage scalars->A0, Wm1->B0/B1, sY
  if (t < ET) *(float4*)(sY + 4 * t) = *(const float4*)(x2 + (e0 + t) * 4);
#pragma unroll
  for (int r = 0; r < 4; ++r) {
    int i = r * TPB + t; int e = i >> 4; int j4 = (i & 15) << 2;
    *(float4*)(sA0 + e * SAS + j4) = *(const float4*)(scalars + (e0 + e) * 64 + j4);
  }
  stageB(Wm1, 64, 0, sBB[0], t);
  stageB(Wm1, 64, 32, sBB[1], t);
  __syncthreads();                                               // BAR0

  const float4 yv0 = *(const float4*)(sY + eh * 4);
  const float4 yv1 = *(const float4*)(sY + (eh + 32) * 4);

  // ---- P1: stage Wm2->B2/B3; h1 = cst*silu(A0 @ Wm1 / 8) -> A1
  stageB(Wm2, 64, 0, sBB[2], t);
  stageB(Wm2, 64, 32, sBB[3], t);
  {
    float4 r0, r1;
    gemm2(sA0, sBB[0], eh, eh + 32, cg, r0, r1);
    *(float4*)(sA1 + eh * SAS + 4 * cg)        = siluq(r0, cst);
    *(float4*)(sA1 + (eh + 32) * SAS + 4 * cg) = siluq(r1, cst);
    gemm2(sA0, sBB[1], eh, eh + 32, cg, r0, r1);
    *(float4*)(sA1 + eh * SAS + 32 + 4 * cg)        = siluq(r0, cst);
    *(float4*)(sA1 + (eh + 32) * SAS + 32 + 4 * cg) = siluq(r1, cst);
  }
  __syncthreads();                                               // BAR1

  // ---- P2: stage Wm3[0:64]->B0/B1; h2 = cst*silu(A1 @ Wm2 / 8) -> A0
  stageB(Wm3, 128, 0, sBB[0], t);
  stageB(Wm3, 128, 32, sBB[1], t);
  {
    float4 r0, r1;
    gemm2(sA1, sBB[2], eh, eh + 32, cg, r0, r1);
    *(float4*)(sA0 + eh * SAS + 4 * cg)        = siluq(r0, cst);
    *(float4*)(sA0 + (eh + 32) * SAS + 4 * cg) = siluq(r1, cst);
    gemm2(sA1, sBB[3], eh, eh + 32, cg, r0, r1);
    *(float4*)(sA0 + eh * SAS + 32 + 4 * cg)        = siluq(r0, cst);
    *(float4*)(sA0 + (eh + 32) * SAS + 32 + 4 * cg) = siluq(r1, cst);
  }
  __syncthreads();                                               // BAR2

  // ---- P3: stage Wm3[64:128]->B2/B3; wts blocks 0,1; build s0 -> A1
  stageB(Wm3, 128, 64, sBB[2], t);
  stageB(Wm3, 128, 96, sBB[3], t);
  float4 wq[2][4];
  {
    float4 r0, r1;
    gemm2(sA0, sBB[0], eh, eh + 32, cg, r0, r1);
    wq[0][0] = muls(r0, 0.125f); wq[1][0] = muls(r1, 0.125f);
    gemm2(sA0, sBB[1], eh, eh + 32, cg, r0, r1);
    wq[0][1] = muls(r0, 0.125f); wq[1][1] = muls(r1, 0.125f);
  }
#pragma unroll
  for (int r = 0; r < 4; ++r) {
    int i = r * TPB + t; int e = i >> 4; int j4 = (i & 15) << 2;
    const float* src = (j4 < 32) ? (x1a + (e0 + e) * 128 + j4)
                                 : (x1b + (e0 + e) * 128 + j4 - 32);
    *(float4*)(sA1 + e * SAS + j4) = *(const float4*)src;
  }
  __syncthreads();                                               // BAR3

  // ---- P4: stage w0->B0, w2->B1; wts blocks 2,3; load x1-tail into regs
  stageB(w0, 32, 0, sBB[0], t);
  stageB(w2, 32, 0, sBB[1], t);
  float xw[4][12];
#pragma unroll
  for (int r = 0; r < 4; ++r) {
    int i = r * TPB + t; int e = i >> 4; int m = i & 15;
    const float* src = ((m < 8) ? x1a : x1b) + (e0 + e) * 128 + 32 + 12 * (m & 7);
    float4 va = *(const float4*)(src);
    float4 vb = *(const float4*)(src + 4);
    float4 vc = *(const float4*)(src + 8);
    xw[r][0] = va.x; xw[r][1]  = va.y; xw[r][2]  = va.z; xw[r][3]  = va.w;
    xw[r][4] = vb.x; xw[r][5]  = vb.y; xw[r][6]  = vb.z; xw[r][7]  = vb.w;
    xw[r][8] = vc.x; xw[r][9]  = vc.y; xw[r][10] = vc.z; xw[r][11] = vc.w;
  }
  {
    float4 r0, r1;
    gemm2(sA0, sBB[2], eh, eh + 32, cg, r0, r1);
    wq[0][2] = muls(r0, 0.125f); wq[1][2] = muls(r1, 0.125f);
    gemm2(sA0, sBB[3], eh, eh + 32, cg, r0, r1);
    wq[0][3] = muls(r0, 0.125f); wq[1][3] = muls(r1, 0.125f);
  }
  __syncthreads();                                               // BAR4

  // ---- P5: stage w1->B2, w3->B3; m0 = s0@w0, p2 = s0@w2; write t1 -> A0
  stageB(w1, 32, 0, sBB[2], t);
  stageB(w3, 32, 0, sBB[3], t);
  float4 m0q[2], p2q[2];
  gemm2(sA1, sBB[0], eh, eh + 32, cg, m0q[0], m0q[1]);
  gemm2(sA1, sBB[1], eh, eh + 32, cg, p2q[0], p2q[1]);
#pragma unroll
  for (int r = 0; r < 4; ++r) {
    int i = r * TPB + t; int e = i >> 4; int m = i & 15;
    const float* yr = sY + e * 4;
    float4 tv;
    tv.x = xw[r][0] * yr[1] + xw[r][1]  * yr[2] + xw[r][2]  * yr[3];
    tv.y = xw[r][3] * yr[1] + xw[r][4]  * yr[2] + xw[r][5]  * yr[3];
    tv.z = xw[r][6] * yr[1] + xw[r][7]  * yr[2] + xw[r][8]  * yr[3];
    tv.w = xw[r][9] * yr[1] + xw[r][10] * yr[2] + xw[r][11] * yr[3];
    *(float4*)(sA0 + e * SAS + 4 * m) = tv;
  }
  __syncthreads();                                               // BAR5

  // ---- P6: stage C0->B0, C1top->B1; m1 = t1@w1; s1_0 -> A1; p2g -> s32
  stageB(C0, 32, 0, sBB[0], t);
  stageB32(C1, 0, sBB[1], t);
  float4 m1q[2];
  gemm2(sA0, sBB[2], eh, eh + 32, cg, m1q[0], m1q[1]);
  S1K(sA1, 0);
  put32(s32, eh,      cg, cmul(p2q[0], wq[0][2], pw));
  put32(s32, eh + 32, cg, cmul(p2q[1], wq[1][2], pw));
  __syncthreads();                                               // BAR6

  // ---- P7: stage C1bot->B2; t3_0 = s1_0@w3; q2 = p2g@C1top; M0 -> A0
  stageB32(C1, 32, sBB[2], t);
  float4 t3[2], q2q[2];
  gemm2(sA1, sBB[3], eh, eh + 32, cg, t3[0], t3[1]);
  gemm32(s32, sBB[1], eh, eh + 32, cg, q2q[0], q2q[1]);
  *(float4*)(sA0 + eh * SAS + 4 * cg)             = cmul(m0q[0], wq[0][0], pw * yv0.x);
  *(float4*)(sA0 + eh * SAS + 32 + 4 * cg)        = cmul(m1q[0], wq[0][1], pws3);
  *(float4*)(sA0 + (eh + 32) * SAS + 4 * cg)      = cmul(m0q[1], wq[1][0], pw * yv1.x);
  *(float4*)(sA0 + (eh + 32) * SAS + 32 + 4 * cg) = cmul(m1q[1], wq[1][1], pws3);
  __syncthreads();                                               // BAR7

  // ---- P8: o0 = M0@C0; t3g_0 -> B1; s1_1 -> A1
  float4 o0q[2];
  gemm2(sA0, sBB[0], eh, eh + 32, cg, o0q[0], o0q[1]);
  put32(sBB[1], eh,      cg, cmul(t3[0], wq[0][3], pw * yv0.x));
  put32(sBB[1], eh + 32, cg, cmul(t3[1], wq[1][3], pw * yv1.x));
  S1K(sA1, 1);
  __syncthreads();                                               // BAR8

  // ---- P9: q3_0 -> o1(k=0); t3_1 = s1_1@w3; s1_2 -> A0
  float o1v[2][12];
  {
    float4 r0, r1;
    gemm32(sBB[1], sBB[2], eh, eh + 32, cg, r0, r1);
    COMBINE(0, r0, r1);
  }
  gemm2(sA1, sBB[3], eh, eh + 32, cg, t3[0], t3[1]);
  S1K(sA0, 2);
  __syncthreads();                                               // BAR9

  // ---- P10: t3_2 = s1_2@w3; t3g_1 -> s32
  put32(s32, eh,      cg, cmul(t3[0], wq[0][3], pw * yv0.x));
  put32(s32, eh + 32, cg, cmul(t3[1], wq[1][3], pw * yv1.x));
  float4 t32a, t32b;
  gemm2(sA0, sBB[3], eh, eh + 32, cg, t32a, t32b);
  __syncthreads();                                               // BAR10

  // ---- P11: q3_1 -> o1(k=1); t3g_2 -> B1
  {
    float4 r0, r1;
    gemm32(s32, sBB[2], eh, eh + 32, cg, r0, r1);
    COMBINE(1, r0, r1);
  }
  put32(sBB[1], eh,      cg, cmul(t32a, wq[0][3], pw * yv0.x));
  put32(sBB[1], eh + 32, cg, cmul(t32b, wq[1][3], pw * yv1.x));
  __syncthreads();                                               // BAR11

  // ---- P12: q3_2 -> o1(k=2); single contiguous store pass
  {
    float4 r0, r1;
    gemm32(sBB[1], sBB[2], eh, eh + 32, cg, r0, r1);
    COMBINE(2, r0, r1);
  }
#pragma unroll
  for (int ei = 0; ei < 2; ++ei) {
    long eg = e0 + eh + 32 * ei;
    float* ob = out + eg * 128;
    *(float4*)(ob + 4 * cg) = o0q[ei];
    float* o1b = ob + 32 + 12 * cg;
    *(float4*)(o1b)     = make_float4(o1v[ei][0], o1v[ei][1], o1v[ei][2],  o1v[ei][3]);
    *(float4*)(o1b + 4) = make_float4(o1v[ei][4], o1v[ei][5], o1v[ei][6],  o1v[ei][7]);
    *(float4*)(o1b + 8) = make_float4(o1v[ei][8], o1v[ei][9], o1v[ei][10], o1v[ei][11]);
  }
}

// ---------------------------------------------------------------------------
extern "C" void kernel_launch(void* const* d_in, const int* in_sizes, int n_in,
                              void* d_out, int out_size, void* d_ws, size_t ws_size,
                              hipStream_t stream) {
  const float* x1a     = (const float*)d_in[0];
  const float* x1b     = (const float*)d_in[1];
  const float* x2      = (const float*)d_in[2];
  const float* scalars = (const float*)d_in[3];
  const float* w0      = (const float*)d_in[4];
  const float* w1      = (const float*)d_in[5];
  const float* w2      = (const float*)d_in[6];
  const float* w3      = (const float*)d_in[7];
  const float* Wl0     = (const float*)d_in[8];
  const float* Wl1     = (const float*)d_in[9];
  const float* Wm1     = (const float*)d_in[10];
  const float* Wm2     = (const float*)d_in[11];
  const float* Wm3     = (const float*)d_in[12];
  const float* Wf0     = (const float*)d_in[13];
  const float* Wf1     = (const float*)d_in[14];
  float* out = (float*)d_out;

  double* cst = (double*)d_ws;
  float* C0 = (float*)d_ws + 128;   // 512 B offset: keeps C0/C1 16B-aligned
  float* C1 = C0 + 64 * 32;

  const int E = in_sizes[0] / 128;  // 200000
  const int nblocks = E / ET;       // 3125

  zero_cst_kernel<<<1, 64, 0, stream>>>(cst);
  cst_accum_kernel<<<64, 256, 0, stream>>>(cst);
  prep_C_kernel<<<2, 256, 0, stream>>>(Wl0, Wf0, Wl1, Wf1, C0, C1);
  fused_tp<<<nblocks, TPB, 0, stream>>>(x1a, x1b, x2, scalars, w0, w1, w2, w3,
                                        Wm1, Wm2, Wm3, C0, C1, cst, out);
}

// Round 2
// 542.256 us; speedup vs baseline: 2.0939x; 2.0939x over previous
//
#include <hip/hip_runtime.h>
#include <math.h>

// ============================================================================
// ConcatenatedIrrepsTensorProduct — fused fp32, round 4.
//
// Round-3 post-mortem: spill (VGPR cap 128, FETCH 1.25GB/WRITE 1.95GB scratch
// round-trips, VALUBusy 15%). Round-2 (282us) re-diagnosed as LDS-READ-BW
// bound: ~22GB LDS instr-bytes at ~69-79 TB/s ceiling == the 282us.
// Round 4 attacks LDS bytes/FMA with a strict register budget:
//   - ET=128, 4 events/thread (EPT=4): B-reads amortized over 2x events.
//     Tail 64 events via EPT=2 instantiation (200000 = 1562*128 + 64).
//   - dual-B gemms (one A read feeds two B slots): h1,h2,wts01,wts23,m0|p2.
//   - o1 split (round-3-verified algebra): o1[e,w,k] = y1k*q2 + q3k;
//     q2 once, q3k via k=32 gemms on 32-wide tiles held in sA cols 0..31
//     (stride 68 -> conflict-free, no extra LDS, no swizzle).
//   - registers: no xw cache (tail re-read as 3x float4/window from L2),
//     o0 stored immediately, gates folded (p2g,wq3g). k-loop live ~112 VGPR.
// LDS: sA 128x68 (34816) + 2 B slots (16384) + sY (2048) = 53248 B
//      -> 3 blocks/CU (159.7KB of 160KB), 12 waves/CU. launch_bounds(256,3).
// LDS reads ~12GB (was 22GB). Predict fused_tp ~190-215us.
// ============================================================================

#define TPB 256
#define SAS 68   // sA row stride in floats: rows 16B-aligned, b128 conflict-free

#define FMA4(acc, s, b)                                         \
  acc.x = fmaf((s), (b).x, acc.x); acc.y = fmaf((s), (b).y, acc.y); \
  acc.z = fmaf((s), (b).z, acc.z); acc.w = fmaf((s), (b).w, acc.w)

// ---------------------------------------------------------------------------
// prep: SILU_CST integral (fp64 trapz identical to reference's np.trapz)
// ---------------------------------------------------------------------------
__global__ void zero_cst_kernel(double* cst) {
  if (threadIdx.x == 0) cst[0] = 0.0;
}

__global__ void cst_accum_kernel(double* cst) {
  __shared__ double red[256];
  double sum = 0.0;
  for (long i = (long)blockIdx.x * 256 + threadIdx.x; i <= 200000; i += 64L * 256) {
    double z = -12.0 + (double)i * (24.0 / 200000.0);
    double s = z / (1.0 + exp(-z));
    double phi = exp(-0.5 * z * z) * 0.3989422804014327;
    double f = s * s * phi;
    if (i == 0 || i == 200000) f *= 0.5;
    sum += f;
  }
  red[threadIdx.x] = sum;
  __syncthreads();
  for (int off = 128; off > 0; off >>= 1) {
    if (threadIdx.x < (unsigned)off) red[threadIdx.x] += red[threadIdx.x + off];
    __syncthreads();
  }
  if (threadIdx.x == 0) atomicAdd(cst, red[0]);
}

// ---------------------------------------------------------------------------
// prep: C0 = Wl0@Wf0 /(8*sqrt32), C1 = Wl1@Wf1 /(8*sqrt32)   (64x32 each)
// ---------------------------------------------------------------------------
__global__ void prep_C_kernel(const float* __restrict__ Wl0, const float* __restrict__ Wf0,
                              const float* __restrict__ Wl1, const float* __restrict__ Wf1,
                              float* __restrict__ C0, float* __restrict__ C1) {
  const float* Wl = blockIdx.x ? Wl1 : Wl0;
  const float* Wf = blockIdx.x ? Wf1 : Wf0;
  float* C = blockIdx.x ? C1 : C0;
  for (int i = threadIdx.x; i < 64 * 32; i += 256) {
    int u = i >> 5, w = i & 31;
    float acc = 0.f;
#pragma unroll
    for (int v = 0; v < 32; ++v) acc = fmaf(Wl[u * 32 + v], Wf[v * 32 + w], acc);
    C[i] = acc * 0.022097086912079612f;  // 1/(sqrt(64)*sqrt(32))
  }
}

// ---------------------------------------------------------------------------
// device helpers
// ---------------------------------------------------------------------------
__device__ __forceinline__ void stageB(const float* __restrict__ g, int ncols, int col0,
                                       float* __restrict__ sB, int t) {
  // copy 64 x 32 column block of row-major [64][ncols] into sB[c*32+j]
#pragma unroll
  for (int r = 0; r < 2; ++r) {
    int i = (r * TPB + t) * 4;     // 0..2044 step 4
    int c = i >> 5, j = i & 31;
    *(float4*)(sB + i) = *(const float4*)(g + c * ncols + col0 + j);
  }
}

// k=64 gemm, one B slot. out[i] = cols 4cg..4cg+3 of event eh+32i.
template <int EPT>
__device__ __forceinline__ void gemm_one(const float* __restrict__ sA,
                                         const float* __restrict__ sB,
                                         int eh, int cg, float4 (&out)[EPT]) {
  float4 acc[EPT];
#pragma unroll
  for (int i = 0; i < EPT; ++i) acc[i] = make_float4(0.f, 0.f, 0.f, 0.f);
  const float* bp = sB + 4 * cg;
#pragma unroll 4
  for (int c4 = 0; c4 < 16; ++c4) {
    const float* bb = bp + c4 * 128;
    float4 b0 = *(const float4*)(bb);
    float4 b1 = *(const float4*)(bb + 32);
    float4 b2 = *(const float4*)(bb + 64);
    float4 b3 = *(const float4*)(bb + 96);
#pragma unroll
    for (int i = 0; i < EPT; ++i) {
      float4 a = *(const float4*)(sA + (eh + 32 * i) * SAS + 4 * c4);
      FMA4(acc[i], a.x, b0);
      FMA4(acc[i], a.y, b1);
      FMA4(acc[i], a.z, b2);
      FMA4(acc[i], a.w, b3);
    }
  }
#pragma unroll
  for (int i = 0; i < EPT; ++i) out[i] = acc[i];
}

// k=64 gemm, two B slots sharing the A reads.
template <int EPT>
__device__ __forceinline__ void gemm_dual(const float* __restrict__ sA,
                                          const float* __restrict__ sB0,
                                          const float* __restrict__ sB1,
                                          int eh, int cg,
                                          float4 (&out0)[EPT], float4 (&out1)[EPT]) {
  float4 a0[EPT], a1[EPT];
#pragma unroll
  for (int i = 0; i < EPT; ++i) {
    a0[i] = make_float4(0.f, 0.f, 0.f, 0.f);
    a1[i] = make_float4(0.f, 0.f, 0.f, 0.f);
  }
  const float* bp0 = sB0 + 4 * cg;
  const float* bp1 = sB1 + 4 * cg;
#pragma unroll 2
  for (int c4 = 0; c4 < 16; ++c4) {
    const float* b0b = bp0 + c4 * 128;
    const float* b1b = bp1 + c4 * 128;
    float4 B00 = *(const float4*)(b0b);
    float4 B01 = *(const float4*)(b0b + 32);
    float4 B02 = *(const float4*)(b0b + 64);
    float4 B03 = *(const float4*)(b0b + 96);
    float4 B10 = *(const float4*)(b1b);
    float4 B11 = *(const float4*)(b1b + 32);
    float4 B12 = *(const float4*)(b1b + 64);
    float4 B13 = *(const float4*)(b1b + 96);
#pragma unroll
    for (int i = 0; i < EPT; ++i) {
      float4 a = *(const float4*)(sA + (eh + 32 * i) * SAS + 4 * c4);
      FMA4(a0[i], a.x, B00); FMA4(a1[i], a.x, B10);
      FMA4(a0[i], a.y, B01); FMA4(a1[i], a.y, B11);
      FMA4(a0[i], a.z, B02); FMA4(a1[i], a.z, B12);
      FMA4(a0[i], a.w, B03); FMA4(a1[i], a.w, B13);
    }
  }
#pragma unroll
  for (int i = 0; i < EPT; ++i) { out0[i] = a0[i]; out1[i] = a1[i]; }
}

// k=32 gemm: A = sA cols 0..31 (stride SAS), B rows at sBbase (32 rows).
template <int EPT>
__device__ __forceinline__ void gemm_k32(const float* __restrict__ sA,
                                         const float* __restrict__ sBbase,
                                         int eh, int cg, float4 (&out)[EPT]) {
  float4 acc[EPT];
#pragma unroll
  for (int i = 0; i < EPT; ++i) acc[i] = make_float4(0.f, 0.f, 0.f, 0.f);
  const float* bp = sBbase + 4 * cg;
#pragma unroll 4
  for (int c4 = 0; c4 < 8; ++c4) {
    const float* bb = bp + c4 * 128;
    float4 b0 = *(const float4*)(bb);
    float4 b1 = *(const float4*)(bb + 32);
    float4 b2 = *(const float4*)(bb + 64);
    float4 b3 = *(const float4*)(bb + 96);
#pragma unroll
    for (int i = 0; i < EPT; ++i) {
      float4 a = *(const float4*)(sA + (eh + 32 * i) * SAS + 4 * c4);
      FMA4(acc[i], a.x, b0);
      FMA4(acc[i], a.y, b1);
      FMA4(acc[i], a.z, b2);
      FMA4(acc[i], a.w, b3);
    }
  }
#pragma unroll
  for (int i = 0; i < EPT; ++i) out[i] = acc[i];
}

__device__ __forceinline__ float silu1(float x, float cst) {
  x *= 0.125f;
  return cst * x / (1.f + __expf(-x));
}

__device__ __forceinline__ float4 siluq(float4 v, float cst) {
  return make_float4(silu1(v.x, cst), silu1(v.y, cst), silu1(v.z, cst), silu1(v.w, cst));
}

__device__ __forceinline__ float4 muls(float4 a, float s) {
  return make_float4(a.x * s, a.y * s, a.z * s, a.w * s);
}

__device__ __forceinline__ float4 cmul(float4 a, float4 b, float s) {
  return make_float4(s * a.x * b.x, s * a.y * b.y, s * a.z * b.z, s * a.w * b.w);
}

__device__ __forceinline__ float4 emul(float4 a, float4 b) {
  return make_float4(a.x * b.x, a.y * b.y, a.z * b.z, a.w * b.w);
}

// k-slice of a 12-float tail window: unit j's elems are w[3j..3j+2]
__device__ __forceinline__ float4 pick3(float4 va, float4 vb, float4 vc, int k) {
  if (k == 0) return make_float4(va.x, va.w, vb.z, vc.y);
  if (k == 1) return make_float4(va.y, vb.x, vb.w, vc.z);
  return make_float4(va.z, vb.y, vc.x, vc.w);
}

// ---------------------------------------------------------------------------
// fused main kernel. EPT events per thread (eh + 32*i), ET = 32*EPT per block.
// ---------------------------------------------------------------------------
template <int EPT>
__global__ __launch_bounds__(TPB, 3) void fused_tp(
    const float* __restrict__ x1a, const float* __restrict__ x1b,
    const float* __restrict__ x2, const float* __restrict__ scalars,
    const float* __restrict__ w0, const float* __restrict__ w1,
    const float* __restrict__ w2, const float* __restrict__ w3,
    const float* __restrict__ Wm1, const float* __restrict__ Wm2,
    const float* __restrict__ Wm3, const float* __restrict__ C0,
    const float* __restrict__ C1, const double* __restrict__ cstp,
    float* __restrict__ out, long ebase) {
  constexpr int ET = 32 * EPT;
  __shared__ __align__(16) float sA[ET * SAS];
  __shared__ __align__(16) float sB0[64 * 32];
  __shared__ __align__(16) float sB1[64 * 32];
  __shared__ __align__(16) float sY[ET * 4];

  const int t  = threadIdx.x;
  const int cg = t & 7;            // 0..7  column group (4 cols)
  const int eh = t >> 3;           // 0..31 base event
  const long e0 = ebase + (long)blockIdx.x * ET;
  const float cst = (float)(1.0 / sqrt(cstp[0] * (24.0 / 200000.0)));

  const float pw   = 0.125f;
  const float pws3 = 0.125f * 0.57735026918962576f;

  // ---- P0: sY, scalars -> sA, Wm1 -> B0/B1
  if (t < ET) *(float4*)(sY + 4 * t) = *(const float4*)(x2 + (e0 + t) * 4);
#pragma unroll
  for (int r = 0; r < ET / 16; ++r) {
    int i = r * TPB + t; int e = i >> 4; int j4 = (i & 15) << 2;
    *(float4*)(sA + e * SAS + j4) = *(const float4*)(scalars + (e0 + e) * 64 + j4);
  }
  stageB(Wm1, 64, 0, sB0, t);
  stageB(Wm1, 64, 32, sB1, t);
  __syncthreads();                                               // BAR0

  float4 yv[EPT];
#pragma unroll
  for (int i = 0; i < EPT; ++i) yv[i] = *(const float4*)(sY + (eh + 32 * i) * 4);

  float4 g0[EPT], g1[EPT];

  // ---- P1: h1 = cst*silu(scalars @ Wm1 / 8)
  gemm_dual<EPT>(sA, sB0, sB1, eh, cg, g0, g1);
  __syncthreads();                                               // BAR1
  // ---- P2: h1 -> sA; stage Wm2
#pragma unroll
  for (int i = 0; i < EPT; ++i) {
    int e = eh + 32 * i;
    *(float4*)(sA + e * SAS + 4 * cg)      = siluq(g0[i], cst);
    *(float4*)(sA + e * SAS + 32 + 4 * cg) = siluq(g1[i], cst);
  }
  stageB(Wm2, 64, 0, sB0, t);
  stageB(Wm2, 64, 32, sB1, t);
  __syncthreads();                                               // BAR2

  // ---- P3: h2 = cst*silu(h1 @ Wm2 / 8)
  gemm_dual<EPT>(sA, sB0, sB1, eh, cg, g0, g1);
  __syncthreads();                                               // BAR3
  // ---- P4: h2 -> sA; stage Wm3[:, 0:64]
#pragma unroll
  for (int i = 0; i < EPT; ++i) {
    int e = eh + 32 * i;
    *(float4*)(sA + e * SAS + 4 * cg)      = siluq(g0[i], cst);
    *(float4*)(sA + e * SAS + 32 + 4 * cg) = siluq(g1[i], cst);
  }
  stageB(Wm3, 128, 0, sB0, t);
  stageB(Wm3, 128, 32, sB1, t);
  __syncthreads();                                               // BAR4

  // ---- P5: gate blocks 0,1 (m0-gate, m1-gate)
  float4 wq0[EPT], wq1[EPT], wq2[EPT], wq3[EPT];
  gemm_dual<EPT>(sA, sB0, sB1, eh, cg, g0, g1);
#pragma unroll
  for (int i = 0; i < EPT; ++i) { wq0[i] = muls(g0[i], 0.125f); wq1[i] = muls(g1[i], 0.125f); }
  __syncthreads();                                               // BAR5
  // ---- P6: stage Wm3[:, 64:128]
  stageB(Wm3, 128, 64, sB0, t);
  stageB(Wm3, 128, 96, sB1, t);
  __syncthreads();                                               // BAR6
  // ---- P7: gate blocks 2,3 (p2-gate, t3-gate)
  gemm_dual<EPT>(sA, sB0, sB1, eh, cg, g0, g1);
#pragma unroll
  for (int i = 0; i < EPT; ++i) { wq2[i] = muls(g0[i], 0.125f); wq3[i] = muls(g1[i], 0.125f); }
  __syncthreads();                                               // BAR7

  // ---- P8: s0 -> sA; stage w0, w2
#pragma unroll
  for (int r = 0; r < ET / 16; ++r) {
    int i = r * TPB + t; int e = i >> 4; int j4 = (i & 15) << 2;
    const float* src = (j4 < 32) ? (x1a + (e0 + e) * 128 + j4)
                                 : (x1b + (e0 + e) * 128 + j4 - 32);
    *(float4*)(sA + e * SAS + j4) = *(const float4*)src;
  }
  stageB(w0, 32, 0, sB0, t);
  stageB(w2, 32, 0, sB1, t);
  __syncthreads();                                               // BAR8

  // ---- P9: m0 = s0@w0, p2 = s0@w2 (shared A); fold gates
  float4 m0q[EPT], p2g[EPT], wq3g[EPT];
  {
    float4 p2q[EPT];
    gemm_dual<EPT>(sA, sB0, sB1, eh, cg, m0q, p2q);
#pragma unroll
    for (int i = 0; i < EPT; ++i) {
      p2g[i]  = cmul(p2q[i], wq2[i], pw);            // pw * p2 * g2
      wq3g[i] = muls(wq3[i], pw * yv[i].x);          // pw * y0 * g3
    }
  }
  __syncthreads();                                               // BAR9

  // ---- P10: t1 -> sA (tail windows, 3 aligned float4 each); stage w1, C0
#pragma unroll
  for (int r = 0; r < ET / 16; ++r) {
    int i = r * TPB + t; int e = i >> 4; int u4 = i & 15;
    const float* src = ((u4 < 8) ? x1a : x1b) + (e0 + e) * 128 + 32 + 12 * (u4 & 7);
    float4 va = *(const float4*)(src);
    float4 vb = *(const float4*)(src + 4);
    float4 vc = *(const float4*)(src + 8);
    const float* yr = sY + e * 4;
    float4 tv;
    tv.x = va.x * yr[1] + va.y * yr[2] + va.z * yr[3];
    tv.y = va.w * yr[1] + vb.x * yr[2] + vb.y * yr[3];
    tv.z = vb.z * yr[1] + vb.w * yr[2] + vc.x * yr[3];
    tv.w = vc.y * yr[1] + vc.z * yr[2] + vc.w * yr[3];
    *(float4*)(sA + e * SAS + 4 * u4) = tv;
  }
  stageB(w1, 32, 0, sB0, t);
  stageB(C0, 32, 0, sB1, t);
  __syncthreads();                                               // BAR10

  // ---- P11: m1 = t1 @ w1
  float4 m1q[EPT];
  gemm_one<EPT>(sA, sB0, eh, cg, m1q);
  __syncthreads();                                               // BAR11

  // ---- P12: M0 -> sA; stage w3 -> B0
#pragma unroll
  for (int i = 0; i < EPT; ++i) {
    int e = eh + 32 * i;
    *(float4*)(sA + e * SAS + 4 * cg)      = cmul(m0q[i], wq0[i], pw * yv[i].x);
    *(float4*)(sA + e * SAS + 32 + 4 * cg) = cmul(m1q[i], wq1[i], pws3);
  }
  stageB(w3, 32, 0, sB0, t);
  __syncthreads();                                               // BAR12

  // ---- P13: o0 = M0 @ C0 -> store immediately (frees regs)
  {
    float4 o0q[EPT];
    gemm_one<EPT>(sA, sB1, eh, cg, o0q);
#pragma unroll
    for (int i = 0; i < EPT; ++i) {
      long eg = e0 + eh + 32 * i;
      *(float4*)(out + eg * 128 + 4 * cg) = o0q[i];
    }
  }
  __syncthreads();                                               // BAR13

  // ---- P14: p2g tile -> sA cols 0..31; stage C1 (top rows 0..31 = first 4KB)
#pragma unroll
  for (int i = 0; i < EPT; ++i) {
    int e = eh + 32 * i;
    *(float4*)(sA + e * SAS + 4 * cg) = p2g[i];
  }
  stageB(C1, 32, 0, sB1, t);
  __syncthreads();                                               // BAR14

  // ---- P15: q2 = (pw*p2*g2) @ C1top
  float4 q2[EPT];
  gemm_k32<EPT>(sA, sB1, eh, cg, q2);

  // ---- k-loop: s1k -> sA; t3 = s1k@w3; t3g -> sA[0:32]; q3 = t3g@C1bot
  float o1v[EPT][12];
#pragma unroll
  for (int k = 0; k < 3; ++k) {
    __syncthreads();                                             // guards sA rebuild
#pragma unroll
    for (int r = 0; r < ET / 16; ++r) {
      int i = r * TPB + t; int e = i >> 4; int u4 = i & 15;
      const float* src = ((u4 < 8) ? x1a : x1b) + (e0 + e) * 128 + 32 + 12 * (u4 & 7);
      float4 va = *(const float4*)(src);
      float4 vb = *(const float4*)(src + 4);
      float4 vc = *(const float4*)(src + 8);
      *(float4*)(sA + e * SAS + 4 * u4) = pick3(va, vb, vc, k);
    }
    __syncthreads();
    float4 t3[EPT];
    gemm_one<EPT>(sA, sB0, eh, cg, t3);                          // s1k @ w3
    __syncthreads();
#pragma unroll
    for (int i = 0; i < EPT; ++i) {
      int e = eh + 32 * i;
      *(float4*)(sA + e * SAS + 4 * cg) = emul(t3[i], wq3g[i]);  // pw*y0*g3*t3
    }
    __syncthreads();
    float4 q3[EPT];
    gemm_k32<EPT>(sA, sB1 + 1024, eh, cg, q3);                   // @ C1bot
#pragma unroll
    for (int i = 0; i < EPT; ++i) {
      float yl = (k == 0) ? yv[i].y : (k == 1) ? yv[i].z : yv[i].w;
      o1v[i][0 + k] = yl * q2[i].x + q3[i].x;
      o1v[i][3 + k] = yl * q2[i].y + q3[i].y;
      o1v[i][6 + k] = yl * q2[i].z + q3[i].z;
      o1v[i][9 + k] = yl * q2[i].w + q3[i].w;
    }
  }

  // ---- o1 store: 3 contiguous float4 per (thread, event)
#pragma unroll
  for (int i = 0; i < EPT; ++i) {
    long eg = e0 + eh + 32 * i;
    float* o1b = out + eg * 128 + 32 + 12 * cg;
    *(float4*)(o1b)     = make_float4(o1v[i][0], o1v[i][1], o1v[i][2],  o1v[i][3]);
    *(float4*)(o1b + 4) = make_float4(o1v[i][4], o1v[i][5], o1v[i][6],  o1v[i][7]);
    *(float4*)(o1b + 8) = make_float4(o1v[i][8], o1v[i][9], o1v[i][10], o1v[i][11]);
  }
}

// ---------------------------------------------------------------------------
extern "C" void kernel_launch(void* const* d_in, const int* in_sizes, int n_in,
                              void* d_out, int out_size, void* d_ws, size_t ws_size,
                              hipStream_t stream) {
  const float* x1a     = (const float*)d_in[0];
  const float* x1b     = (const float*)d_in[1];
  const float* x2      = (const float*)d_in[2];
  const float* scalars = (const float*)d_in[3];
  const float* w0      = (const float*)d_in[4];
  const float* w1      = (const float*)d_in[5];
  const float* w2      = (const float*)d_in[6];
  const float* w3      = (const float*)d_in[7];
  const float* Wl0     = (const float*)d_in[8];
  const float* Wl1     = (const float*)d_in[9];
  const float* Wm1     = (const float*)d_in[10];
  const float* Wm2     = (const float*)d_in[11];
  const float* Wm3     = (const float*)d_in[12];
  const float* Wf0     = (const float*)d_in[13];
  const float* Wf1     = (const float*)d_in[14];
  float* out = (float*)d_out;

  double* cst = (double*)d_ws;
  float* C0 = (float*)d_ws + 128;   // 512 B offset: keeps C0/C1 16B-aligned
  float* C1 = C0 + 64 * 32;

  const int E = in_sizes[0] / 128;  // 200000
  const int nfull = E / 128;        // 1562 blocks of 128 events
  const int rem   = E - nfull * 128;// 64

  zero_cst_kernel<<<1, 64, 0, stream>>>(cst);
  cst_accum_kernel<<<64, 256, 0, stream>>>(cst);
  prep_C_kernel<<<2, 256, 0, stream>>>(Wl0, Wf0, Wl1, Wf1, C0, C1);
  fused_tp<4><<<nfull, TPB, 0, stream>>>(x1a, x1b, x2, scalars, w0, w1, w2, w3,
                                         Wm1, Wm2, Wm3, C0, C1, cst, out, 0L);
  if (rem > 0) {
    fused_tp<2><<<rem / 64, TPB, 0, stream>>>(x1a, x1b, x2, scalars, w0, w1, w2, w3,
                                              Wm1, Wm2, Wm3, C0, C1, cst, out,
                                              (long)nfull * 128);
  }
}

// Round 3
// 450.336 us; speedup vs baseline: 2.5213x; 1.2041x over previous
//
#include <hip/hip_runtime.h>
#include <math.h>

// ============================================================================
// ConcatenatedIrrepsTensorProduct — fused fp32, round 5.
//
// Measured history: r2 = 282us (4 blk/CU, VALU 59%), r3 = spill disaster,
// r4 = 316us (EPT=4, 3 blk/CU: LDS bytes down but occupancy 38->27% and 3x
// k-loop global traffic; latency exposure beat the LDS savings).
// Round 5 = round-2 structure (ET=64, EPT=2, 34.8KB LDS, 4 blk/CU) plus only
// the verified cheap wins:
//   - o1 split (r4-verified algebra): o1[e,w,k] = y1k*q2 + q3k.
//     q2 = (pw*p2*g2)@C1[0:32] once; q3k = (pw*y0*g3*t3k)@C1[32:64].
//     k-loop: k64+k32 gemm per k (was k64+k64). -5.5% FMA, -15% LDS instrs.
//     32-wide q-tiles live in sA cols 0..31 (stride 68 -> conflict-free,
//     zero extra LDS).
//   - dual-B gemms at the 5 shared-A sites (h1,h2,wts01,wts23,m0|p2):
//     one A read feeds both B slots (-160 ds_read_b128/thread).
//   - o0 held in regs to the single final store pass (r4's early store
//     pushed WRITE 102->186MB).
//   - k-loop rebuilds s1k with exact-byte scalar loads (r2 pattern; r4's
//     float4 windows discarded 2/3 of fetched bytes -> FETCH 393MB).
//   - prep merged into ONE kernel (cst partials per block, no zero pass,
//     no atomics; fused_tp wave 0 butterfly-reduces 64 partials). 4->2
//     launches in the graph.
// LDS: sA 64x68 (17408) + sB0/sB1 (16384) + sY (1024) = 34816 -> 4 blk/CU.
// Predict fused_tp ~245-260us, VALUBusy ~64%, FETCH ~150-200MB, WRITE ~100MB.
// ============================================================================

#define TPB 256
#define SAS 68   // sA row stride in floats: rows 16B-aligned, b128 conflict-free

#define FMA4(acc, s, b)                                         \
  acc.x = fmaf((s), (b).x, acc.x); acc.y = fmaf((s), (b).y, acc.y); \
  acc.z = fmaf((s), (b).z, acc.z); acc.w = fmaf((s), (b).w, acc.w)

// ---------------------------------------------------------------------------
// merged prep kernel:
//   blocks 0..63 : SILU_CST trapz partial sums -> part[bid] (fp64, matches
//                  reference np.trapz up to summation order ~1e-16)
//   blocks 64,65 : C0 = Wl0@Wf0 /(8*sqrt32), C1 = Wl1@Wf1 /(8*sqrt32)
// ---------------------------------------------------------------------------
__global__ void prep_kernel(const float* __restrict__ Wl0, const float* __restrict__ Wf0,
                            const float* __restrict__ Wl1, const float* __restrict__ Wf1,
                            float* __restrict__ C0, float* __restrict__ C1,
                            double* __restrict__ part) {
  if (blockIdx.x < 64) {
    __shared__ double red[256];
    double sum = 0.0;
    for (long i = (long)blockIdx.x * 256 + threadIdx.x; i <= 200000; i += 64L * 256) {
      double z = -12.0 + (double)i * (24.0 / 200000.0);
      double s = z / (1.0 + exp(-z));
      double phi = exp(-0.5 * z * z) * 0.3989422804014327;
      double f = s * s * phi;
      if (i == 0 || i == 200000) f *= 0.5;
      sum += f;
    }
    red[threadIdx.x] = sum;
    __syncthreads();
    for (int off = 128; off > 0; off >>= 1) {
      if (threadIdx.x < (unsigned)off) red[threadIdx.x] += red[threadIdx.x + off];
      __syncthreads();
    }
    if (threadIdx.x == 0) part[blockIdx.x] = red[0];
  } else {
    const int b = blockIdx.x - 64;
    const float* Wl = b ? Wl1 : Wl0;
    const float* Wf = b ? Wf1 : Wf0;
    float* C = b ? C1 : C0;
    for (int i = threadIdx.x; i < 64 * 32; i += 256) {
      int u = i >> 5, w = i & 31;
      float acc = 0.f;
#pragma unroll
      for (int v = 0; v < 32; ++v) acc = fmaf(Wl[u * 32 + v], Wf[v * 32 + w], acc);
      C[i] = acc * 0.022097086912079612f;  // 1/(sqrt(64)*sqrt(32))
    }
  }
}

// ---------------------------------------------------------------------------
// device helpers
// ---------------------------------------------------------------------------
__device__ __forceinline__ void stageB(const float* __restrict__ g, int ncols, int col0,
                                       float* __restrict__ sB, int t) {
  // copy 64 x 32 column block of row-major [64][ncols] into sB[c*32+j]
#pragma unroll
  for (int r = 0; r < 2; ++r) {
    int i = (r * TPB + t) * 4;     // 0..2044 step 4
    int c = i >> 5, j = i & 31;
    *(float4*)(sB + i) = *(const float4*)(g + c * ncols + col0 + j);
  }
}

// k=64 gemm, single B. out0/out1 = cols 4cg..4cg+3 of events e0l/e1l.
__device__ __forceinline__ void gemm2(const float* __restrict__ sA,
                                      const float* __restrict__ sB,
                                      int e0l, int e1l, int cg,
                                      float4& out0, float4& out1) {
  float4 acc0 = make_float4(0.f, 0.f, 0.f, 0.f);
  float4 acc1 = make_float4(0.f, 0.f, 0.f, 0.f);
  const float* a0p = sA + e0l * SAS;
  const float* a1p = sA + e1l * SAS;
  const float* bp  = sB + 4 * cg;
#pragma unroll 4
  for (int c4 = 0; c4 < 16; ++c4) {
    float4 a0 = *(const float4*)(a0p + 4 * c4);
    float4 a1 = *(const float4*)(a1p + 4 * c4);
    const float* bb = bp + c4 * 128;
    float4 b0 = *(const float4*)(bb);
    float4 b1 = *(const float4*)(bb + 32);
    float4 b2 = *(const float4*)(bb + 64);
    float4 b3 = *(const float4*)(bb + 96);
    FMA4(acc0, a0.x, b0); FMA4(acc1, a1.x, b0);
    FMA4(acc0, a0.y, b1); FMA4(acc1, a1.y, b1);
    FMA4(acc0, a0.z, b2); FMA4(acc1, a1.z, b2);
    FMA4(acc0, a0.w, b3); FMA4(acc1, a1.w, b3);
  }
  out0 = acc0;
  out1 = acc1;
}

// k=64 gemm, two B slots sharing the A reads.
// oX0/oX1: event e0l/e1l @ B(X).
__device__ __forceinline__ void gemm2_dual(const float* __restrict__ sA,
                                           const float* __restrict__ sB0,
                                           const float* __restrict__ sB1,
                                           int e0l, int e1l, int cg,
                                           float4& o00, float4& o01,
                                           float4& o10, float4& o11) {
  float4 a00 = make_float4(0.f, 0.f, 0.f, 0.f);
  float4 a01 = make_float4(0.f, 0.f, 0.f, 0.f);
  float4 a10 = make_float4(0.f, 0.f, 0.f, 0.f);
  float4 a11 = make_float4(0.f, 0.f, 0.f, 0.f);
  const float* a0p = sA + e0l * SAS;
  const float* a1p = sA + e1l * SAS;
  const float* bp0 = sB0 + 4 * cg;
  const float* bp1 = sB1 + 4 * cg;
#pragma unroll 2
  for (int c4 = 0; c4 < 16; ++c4) {
    float4 a0 = *(const float4*)(a0p + 4 * c4);
    float4 a1 = *(const float4*)(a1p + 4 * c4);
    const float* b0b = bp0 + c4 * 128;
    const float* b1b = bp1 + c4 * 128;
    float4 B00 = *(const float4*)(b0b);
    float4 B01 = *(const float4*)(b0b + 32);
    float4 B02 = *(const float4*)(b0b + 64);
    float4 B03 = *(const float4*)(b0b + 96);
    float4 B10 = *(const float4*)(b1b);
    float4 B11 = *(const float4*)(b1b + 32);
    float4 B12 = *(const float4*)(b1b + 64);
    float4 B13 = *(const float4*)(b1b + 96);
    FMA4(a00, a0.x, B00); FMA4(a01, a1.x, B00);
    FMA4(a10, a0.x, B10); FMA4(a11, a1.x, B10);
    FMA4(a00, a0.y, B01); FMA4(a01, a1.y, B01);
    FMA4(a10, a0.y, B11); FMA4(a11, a1.y, B11);
    FMA4(a00, a0.z, B02); FMA4(a01, a1.z, B02);
    FMA4(a10, a0.z, B12); FMA4(a11, a1.z, B12);
    FMA4(a00, a0.w, B03); FMA4(a01, a1.w, B03);
    FMA4(a10, a0.w, B13); FMA4(a11, a1.w, B13);
  }
  o00 = a00; o01 = a01; o10 = a10; o11 = a11;
}

// k=32 gemm: A = sA cols 0..31 (stride SAS -> conflict-free), B = 32 rows
// at sBbase (stride 32).
__device__ __forceinline__ void gemm_k32(const float* __restrict__ sA,
                                         const float* __restrict__ sBbase,
                                         int e0l, int e1l, int cg,
                                         float4& out0, float4& out1) {
  float4 acc0 = make_float4(0.f, 0.f, 0.f, 0.f);
  float4 acc1 = make_float4(0.f, 0.f, 0.f, 0.f);
  const float* a0p = sA + e0l * SAS;
  const float* a1p = sA + e1l * SAS;
  const float* bp  = sBbase + 4 * cg;
#pragma unroll 4
  for (int c4 = 0; c4 < 8; ++c4) {
    float4 a0 = *(const float4*)(a0p + 4 * c4);
    float4 a1 = *(const float4*)(a1p + 4 * c4);
    const float* bb = bp + c4 * 128;
    float4 b0 = *(const float4*)(bb);
    float4 b1 = *(const float4*)(bb + 32);
    float4 b2 = *(const float4*)(bb + 64);
    float4 b3 = *(const float4*)(bb + 96);
    FMA4(acc0, a0.x, b0); FMA4(acc1, a1.x, b0);
    FMA4(acc0, a0.y, b1); FMA4(acc1, a1.y, b1);
    FMA4(acc0, a0.z, b2); FMA4(acc1, a1.z, b2);
    FMA4(acc0, a0.w, b3); FMA4(acc1, a1.w, b3);
  }
  out0 = acc0;
  out1 = acc1;
}

__device__ __forceinline__ float silu1(float x, float cst) {
  x *= 0.125f;
  return cst * x / (1.f + __expf(-x));
}

__device__ __forceinline__ float4 siluq(float4 v, float cst) {
  return make_float4(silu1(v.x, cst), silu1(v.y, cst), silu1(v.z, cst), silu1(v.w, cst));
}

__device__ __forceinline__ float4 muls(float4 a, float s) {
  return make_float4(a.x * s, a.y * s, a.z * s, a.w * s);
}

__device__ __forceinline__ float4 cmul(float4 a, float4 b, float s) {
  return make_float4(s * a.x * b.x, s * a.y * b.y, s * a.z * b.z, s * a.w * b.w);
}

__device__ __forceinline__ float4 emul(float4 a, float4 b) {
  return make_float4(a.x * b.x, a.y * b.y, a.z * b.z, a.w * b.w);
}

// ---------------------------------------------------------------------------
// fused main kernel — round-2 structure + dual-B + o1 split
// ---------------------------------------------------------------------------
__global__ __launch_bounds__(TPB, 4) void fused_tp(
    const float* __restrict__ x1a, const float* __restrict__ x1b,
    const float* __restrict__ x2, const float* __restrict__ scalars,
    const float* __restrict__ w0, const float* __restrict__ w1,
    const float* __restrict__ w2, const float* __restrict__ w3,
    const float* __restrict__ Wm1, const float* __restrict__ Wm2,
    const float* __restrict__ Wm3, const float* __restrict__ C0,
    const float* __restrict__ C1, const double* __restrict__ part,
    float* __restrict__ out) {
  __shared__ __align__(16) float sA[64 * SAS];   // 17408 B
  __shared__ __align__(16) float sB0[64 * 32];   //  8192 B
  __shared__ __align__(16) float sB1[64 * 32];   //  8192 B
  __shared__ __align__(16) float sY[64 * 4];     //  1024 B
  __shared__ float scst_s;

  const int t  = threadIdx.x;
  const int cg = t & 7;            // 0..7  column group (4 cols)
  const int eh = t >> 3;           // 0..31 first event; second is eh+32
  const long e0 = (long)blockIdx.x * 64;

  const float pw   = 0.125f;
  const float pws3 = 0.125f * 0.57735026918962576f;

  // ---- P0: cst reduce (wave 0); sY; scalars -> sA; Wm1 -> B0/B1
  if (t < 64) {
    double v = part[t];
#pragma unroll
    for (int m = 32; m > 0; m >>= 1) v += __shfl_xor(v, m);
    if (t == 0) scst_s = (float)(1.0 / sqrt(v * (24.0 / 200000.0)));
    *(float4*)(sY + 4 * t) = *(const float4*)(x2 + (e0 + t) * 4);
  }
#pragma unroll
  for (int r = 0; r < 4; ++r) {
    int i = r * TPB + t; int e = i >> 4; int j4 = (i & 15) << 2;
    *(float4*)(sA + e * SAS + j4) = *(const float4*)(scalars + (e0 + e) * 64 + j4);
  }
  stageB(Wm1, 64, 0, sB0, t);
  stageB(Wm1, 64, 32, sB1, t);
  __syncthreads();                                               // BAR0

  const float cst = scst_s;
  const float4 yv0 = *(const float4*)(sY + eh * 4);
  const float4 yv1 = *(const float4*)(sY + (eh + 32) * 4);

  // ---- P1: h1 = cst*silu(scalars @ Wm1 / 8)  (dual: both column halves)
  float4 r00, r01, r10, r11;
  gemm2_dual(sA, sB0, sB1, eh, eh + 32, cg, r00, r01, r10, r11);
  __syncthreads();                                               // BAR1
  // ---- P2: h1 -> sA; stage Wm2
  *(float4*)(sA + eh * SAS + 4 * cg)             = siluq(r00, cst);
  *(float4*)(sA + eh * SAS + 32 + 4 * cg)        = siluq(r10, cst);
  *(float4*)(sA + (eh + 32) * SAS + 4 * cg)      = siluq(r01, cst);
  *(float4*)(sA + (eh + 32) * SAS + 32 + 4 * cg) = siluq(r11, cst);
  stageB(Wm2, 64, 0, sB0, t);
  stageB(Wm2, 64, 32, sB1, t);
  __syncthreads();                                               // BAR2

  // ---- P3: h2 = cst*silu(h1 @ Wm2 / 8)
  gemm2_dual(sA, sB0, sB1, eh, eh + 32, cg, r00, r01, r10, r11);
  __syncthreads();                                               // BAR3
  // ---- P4: h2 -> sA; stage Wm3[:, 0:64]
  *(float4*)(sA + eh * SAS + 4 * cg)             = siluq(r00, cst);
  *(float4*)(sA + eh * SAS + 32 + 4 * cg)        = siluq(r10, cst);
  *(float4*)(sA + (eh + 32) * SAS + 4 * cg)      = siluq(r01, cst);
  *(float4*)(sA + (eh + 32) * SAS + 32 + 4 * cg) = siluq(r11, cst);
  stageB(Wm3, 128, 0, sB0, t);
  stageB(Wm3, 128, 32, sB1, t);
  __syncthreads();                                               // BAR4

  // ---- P5: gate blocks 0,1
  float4 gq0[2], gq1[2], gq2[2], gq3[2];
  gemm2_dual(sA, sB0, sB1, eh, eh + 32, cg, r00, r01, r10, r11);
  gq0[0] = muls(r00, 0.125f); gq0[1] = muls(r01, 0.125f);
  gq1[0] = muls(r10, 0.125f); gq1[1] = muls(r11, 0.125f);
  __syncthreads();                                               // BAR5
  // ---- P6: stage Wm3[:, 64:128]
  stageB(Wm3, 128, 64, sB0, t);
  stageB(Wm3, 128, 96, sB1, t);
  __syncthreads();                                               // BAR6
  // ---- P7: gate blocks 2,3
  gemm2_dual(sA, sB0, sB1, eh, eh + 32, cg, r00, r01, r10, r11);
  gq2[0] = muls(r00, 0.125f); gq2[1] = muls(r01, 0.125f);
  gq3[0] = muls(r10, 0.125f); gq3[1] = muls(r11, 0.125f);
  __syncthreads();                                               // BAR7

  // ---- P8: s0 -> sA; stage w0 -> B0, w2 -> B1
#pragma unroll
  for (int r = 0; r < 4; ++r) {
    int i = r * TPB + t; int e = i >> 4; int j4 = (i & 15) << 2;
    const float* src = (j4 < 32) ? (x1a + (e0 + e) * 128 + j4)
                                 : (x1b + (e0 + e) * 128 + j4 - 32);
    *(float4*)(sA + e * SAS + j4) = *(const float4*)src;
  }
  stageB(w0, 32, 0, sB0, t);
  stageB(w2, 32, 0, sB1, t);
  __syncthreads();                                               // BAR8

  // ---- P9: m0 = s0@w0, p2 = s0@w2 (dual); fold gates
  float4 m0g[2], p2g[2], w3g[2];
  gemm2_dual(sA, sB0, sB1, eh, eh + 32, cg, r00, r01, r10, r11);
  m0g[0] = cmul(r00, gq0[0], pw * yv0.x);   // pw*y0 * m0 * g0
  m0g[1] = cmul(r01, gq0[1], pw * yv1.x);
  p2g[0] = cmul(r10, gq2[0], pw);           // pw * p2 * g2
  p2g[1] = cmul(r11, gq2[1], pw);
  w3g[0] = muls(gq3[0], pw * yv0.x);        // pw*y0 * g3
  w3g[1] = muls(gq3[1], pw * yv1.x);
  __syncthreads();                                               // BAR9

  // ---- P10: t1 -> sA (tail, 3 aligned float4 per window, each byte used
  //           exactly once); stage w1 -> B0, C0 -> B1
#pragma unroll
  for (int r = 0; r < 4; ++r) {
    int i = r * TPB + t; int e = i >> 4; int u4 = i & 15;
    const float* src = ((u4 < 8) ? x1a : x1b) + (e0 + e) * 128 + 32 + 12 * (u4 & 7);
    float4 va = *(const float4*)(src);
    float4 vb = *(const float4*)(src + 4);
    float4 vc = *(const float4*)(src + 8);
    const float* yr = sY + e * 4;
    float4 tv;
    tv.x = va.x * yr[1] + va.y * yr[2] + va.z * yr[3];
    tv.y = va.w * yr[1] + vb.x * yr[2] + vb.y * yr[3];
    tv.z = vb.z * yr[1] + vb.w * yr[2] + vc.x * yr[3];
    tv.w = vc.y * yr[1] + vc.z * yr[2] + vc.w * yr[3];
    *(float4*)(sA + e * SAS + 4 * u4) = tv;
  }
  stageB(w1, 32, 0, sB0, t);
  stageB(C0, 32, 0, sB1, t);
  __syncthreads();                                               // BAR10

  // ---- P11: m1 = t1 @ w1
  float4 m1q[2];
  gemm2(sA, sB0, eh, eh + 32, cg, m1q[0], m1q[1]);
  __syncthreads();                                               // BAR11

  // ---- P12: M0 -> sA  [m0 gated | m1 gated]
  *(float4*)(sA + eh * SAS + 4 * cg)             = m0g[0];
  *(float4*)(sA + eh * SAS + 32 + 4 * cg)        = cmul(m1q[0], gq1[0], pws3);
  *(float4*)(sA + (eh + 32) * SAS + 4 * cg)      = m0g[1];
  *(float4*)(sA + (eh + 32) * SAS + 32 + 4 * cg) = cmul(m1q[1], gq1[1], pws3);
  __syncthreads();                                               // BAR12

  // ---- P13: o0 = M0 @ C0 (held in regs to the final store pass)
  float4 o0q[2];
  gemm2(sA, sB1, eh, eh + 32, cg, o0q[0], o0q[1]);
  __syncthreads();                                               // BAR13

  // ---- P14: p2g -> sA cols 0..31; stage w3 -> B0, C1 (all 64 rows) -> B1
  *(float4*)(sA + eh * SAS + 4 * cg)        = p2g[0];
  *(float4*)(sA + (eh + 32) * SAS + 4 * cg) = p2g[1];
  stageB(w3, 32, 0, sB0, t);
  stageB(C1, 32, 0, sB1, t);
  __syncthreads();                                               // BAR14

  // ---- P15: q2 = p2g @ C1[0:32]
  float4 q2q[2];
  gemm_k32(sA, sB1, eh, eh + 32, cg, q2q[0], q2q[1]);

  // ---- k-loop: s1k -> sA; t3 = s1k@w3; t3g -> sA[0:32]; q3 = t3g@C1[32:64]
  float o1v[2][12];
#pragma unroll
  for (int k = 0; k < 3; ++k) {
    __syncthreads();                     // WAR: q2/q3 reads done before rebuild
#pragma unroll 2
    for (int r = 0; r < 16; ++r) {
      int i = r * TPB + t; int e = i >> 6; int u = i & 63;
      const float* xr = ((u < 32) ? x1a : x1b) + (e0 + e) * 128 + 32 + 3 * (u & 31);
      sA[e * SAS + u] = xr[k];           // exact-byte scalar load (L2-hot)
    }
    __syncthreads();
    float4 t3[2];
    gemm2(sA, sB0, eh, eh + 32, cg, t3[0], t3[1]);               // s1k @ w3
    __syncthreads();
    *(float4*)(sA + eh * SAS + 4 * cg)        = emul(t3[0], w3g[0]);
    *(float4*)(sA + (eh + 32) * SAS + 4 * cg) = emul(t3[1], w3g[1]);
    __syncthreads();
    float4 q3a, q3b;
    gemm_k32(sA, sB1 + 1024, eh, eh + 32, cg, q3a, q3b);         // @ C1[32:64]
    float ya = (k == 0) ? yv0.y : (k == 1) ? yv0.z : yv0.w;
    float yb = (k == 0) ? yv1.y : (k == 1) ? yv1.z : yv1.w;
    o1v[0][0 + k] = ya * q2q[0].x + q3a.x;
    o1v[0][3 + k] = ya * q2q[0].y + q3a.y;
    o1v[0][6 + k] = ya * q2q[0].z + q3a.z;
    o1v[0][9 + k] = ya * q2q[0].w + q3a.w;
    o1v[1][0 + k] = yb * q2q[1].x + q3b.x;
    o1v[1][3 + k] = yb * q2q[1].y + q3b.y;
    o1v[1][6 + k] = yb * q2q[1].z + q3b.z;
    o1v[1][9 + k] = yb * q2q[1].w + q3b.w;
  }

  // ---- single contiguous store pass: 4 float4 per (thread, event)
#pragma unroll
  for (int ei = 0; ei < 2; ++ei) {
    long eg = e0 + eh + 32 * ei;
    float* ob = out + eg * 128;
    *(float4*)(ob + 4 * cg) = o0q[ei];
    float* o1b = ob + 32 + 12 * cg;
    *(float4*)(o1b)     = make_float4(o1v[ei][0], o1v[ei][1], o1v[ei][2],  o1v[ei][3]);
    *(float4*)(o1b + 4) = make_float4(o1v[ei][4], o1v[ei][5], o1v[ei][6],  o1v[ei][7]);
    *(float4*)(o1b + 8) = make_float4(o1v[ei][8], o1v[ei][9], o1v[ei][10], o1v[ei][11]);
  }
}

// ---------------------------------------------------------------------------
extern "C" void kernel_launch(void* const* d_in, const int* in_sizes, int n_in,
                              void* d_out, int out_size, void* d_ws, size_t ws_size,
                              hipStream_t stream) {
  const float* x1a     = (const float*)d_in[0];
  const float* x1b     = (const float*)d_in[1];
  const float* x2      = (const float*)d_in[2];
  const float* scalars = (const float*)d_in[3];
  const float* w0      = (const float*)d_in[4];
  const float* w1      = (const float*)d_in[5];
  const float* w2      = (const float*)d_in[6];
  const float* w3      = (const float*)d_in[7];
  const float* Wl0     = (const float*)d_in[8];
  const float* Wl1     = (const float*)d_in[9];
  const float* Wm1     = (const float*)d_in[10];
  const float* Wm2     = (const float*)d_in[11];
  const float* Wm3     = (const float*)d_in[12];
  const float* Wf0     = (const float*)d_in[13];
  const float* Wf1     = (const float*)d_in[14];
  float* out = (float*)d_out;

  double* part = (double*)d_ws;     // 64 doubles = 512 B
  float* C0 = (float*)d_ws + 128;   // byte 512: keeps C0/C1 16B-aligned
  float* C1 = C0 + 64 * 32;

  const int E = in_sizes[0] / 128;  // 200000
  const int nblocks = E / 64;       // 3125

  prep_kernel<<<66, 256, 0, stream>>>(Wl0, Wf0, Wl1, Wf1, C0, C1, part);
  fused_tp<<<nblocks, TPB, 0, stream>>>(x1a, x1b, x2, scalars, w0, w1, w2, w3,
                                        Wm1, Wm2, Wm3, C0, C1, part, out);
}